// Round 7
// baseline (277.466 us; speedup 1.0000x reference)
//
#include <hip/hip_runtime.h>
#include <hip/hip_bf16.h>

// B=8 IC=8 ID=16 OC=8 OD=16 H=W=32 K=3 ITER=3
// conv as MFMA GEMM per image: A=tw (512 co4 x 576 k), B=im2col(x) (576 k x 1024 pos)
// A-fragments read DIRECTLY from global (L2-hot, 576 KB); only image tile staged in LDS.
// p (64, 512, 32, 32) bf16.  Routing per (b, r, y, x).
// v output: (B, OC, OD, 4, H, W) = 4,194,304 fp32; entropy scalar at out[4194304]

typedef short bf16x8 __attribute__((ext_vector_type(8)));
typedef float f32x4 __attribute__((ext_vector_type(4)));
typedef unsigned int u32x2 __attribute__((ext_vector_type(2)));

__device__ inline float bf2f(unsigned int u) {
    union { unsigned int i; float f; } x;
    x.i = u << 16;
    return x.f;
}
__device__ inline unsigned short f2bf(float f) {
    union { float f; unsigned int u; } x;
    x.f = f;
    unsigned int r = x.u + 0x7fffu + ((x.u >> 16) & 1u);
    return (unsigned short)(r >> 16);
}

// async global->LDS 16B per lane: LDS dest = wave-uniform base + lane*16
__device__ __forceinline__ void gld16(void* lds_uniform, const void* gsrc) {
    __builtin_amdgcn_global_load_lds(
        (const __attribute__((address_space(1))) unsigned int*)gsrc,
        (__attribute__((address_space(3))) unsigned int*)lds_uniform,
        16, 0, 0);
}

// cross-lane helpers (all-lanes-active contexts only)
__device__ inline float dppx1(float x) {
    return __int_as_float(__builtin_amdgcn_update_dpp(0, __float_as_int(x), 0xB1, 0xF, 0xF, false));
}
__device__ inline float dppx2(float x) {
    return __int_as_float(__builtin_amdgcn_update_dpp(0, __float_as_int(x), 0x4E, 0xF, 0xF, false));
}
template <int PATT>
__device__ inline float swzf(float x) {
    return __int_as_float(__builtin_amdgcn_ds_swizzle(__float_as_int(x), PATT));
}
#define SWZ4  0x101F
#define SWZ8  0x201F
#define SWZ16 0x401F
__device__ inline float psum32(float x) {  // x + x[lane^32]
    u32x2 r = __builtin_amdgcn_permlane32_swap(__float_as_uint(x), __float_as_uint(x), false, false);
    return __uint_as_float(r[0]) + __uint_as_float(r[1]);
}

// ---------------- kernel 1: transformed weights, bf16, fragment-major ----------------
// twb[tap][cig][co4][j] : [9][8][512][8] bf16 (cig = ci>>3, j = ci&7; NO xor swizzle)
// A-fragment read: lane(hi,p15) reads 16B at co4=base+p15, cig=hi+s*4 -> 4 x 256B segments
__global__ __launch_bounds__(256) void k_twb(const float* __restrict__ w,
                                             unsigned short* __restrict__ twb) {
    int idx = blockIdx.x * 256 + threadIdx.x;   // 1152 * 256 = 294912 exactly
    int tap = idx >> 15;
    int cig = (idx >> 12) & 7;
    int co4 = (idx >> 3) & 511;
    int j = idx & 7;
    int ci = cig * 8 + j;
    int r = co4 & 3, co = co4 >> 2;
    int s = ci & 3, cicap = ci >> 2;
    int ky = tap / 3, kx = tap % 3;
    int sy, sx;
    switch (r) {
        case 0: sy = ky;      sx = kx;      break;
        case 1: sy = kx;      sx = 2 - ky;  break;
        case 2: sy = 2 - ky;  sx = 2 - kx;  break;
        default: sy = 2 - kx; sx = ky;      break;
    }
    int ss = (s - r) & 3;
    twb[idx] = f2bf(w[(((co * 16 + cicap) * 4 + ss) * 3 + sy) * 3 + sx]);
}

// ---------------- kernel 2: pad + transpose + bf16 + swizzle the input ----------------
// xpad[n][yy][xx][ci'] : [64][34][34][64] bf16 ; ci' = ci ^ ((xx&7)<<3); borders pre-zeroed
__global__ __launch_bounds__(256) void k_prep(const float* __restrict__ xf,
                                              unsigned short* __restrict__ xpad) {
    int n = blockIdx.x >> 5, y = blockIdx.x & 31;
    int tid = threadIdx.x;
    __shared__ float tile[64][33];
#pragma unroll
    for (int it = 0; it < 8; ++it) {
        int ci = it * 8 + (tid >> 5), x = tid & 31;
        tile[ci][x] = xf[((n * 64 + ci) * 32 + y) * 32 + x];
    }
    __syncthreads();
    int xx = 1 + (tid >> 3), g = tid & 7;
    int x = xx - 1;
    int lg = g ^ (xx & 7);
    unsigned short vals[8];
#pragma unroll
    for (int j = 0; j < 8; ++j) vals[j] = f2bf(tile[lg * 8 + j][x]);
    uint4 pk;
    pk.x = (unsigned)vals[0] | ((unsigned)vals[1] << 16);
    pk.y = (unsigned)vals[2] | ((unsigned)vals[3] << 16);
    pk.z = (unsigned)vals[4] | ((unsigned)vals[5] << 16);
    pk.w = (unsigned)vals[6] | ((unsigned)vals[7] << 16);
    *reinterpret_cast<uint4*>(&xpad[(n * 34 + (y + 1)) * 2176 + xx * 64 + g * 8]) = pk;
}

// ---------------- kernel 3: MFMA conv, A-from-global, + fused BN partial stats ----------------
// grid (64 n, 8 yt, 4 cot), 256 threads = 4 waves in 2x2
// wave tile: 64 co4 x 64 pos (4x4 frags 16x16), K = 9 taps x 2 steps of 32
// ONE barrier per block (after xs stage); 9-tap loop fully unrolled, zero barriers.
__global__ __launch_bounds__(256, 3) void k_mconv(const unsigned short* __restrict__ xpad,
                                                  const unsigned short* __restrict__ twb,
                                                  unsigned short* __restrict__ p,
                                                  float* __restrict__ ps) {
    int n = blockIdx.x, yt = blockIdx.y, cot = blockIdx.z;
    int y0 = yt * 4;
    int tid = threadIdx.x, lane = tid & 63, wave = tid >> 6;
    int wm = (wave >> 1) * 64, wn = (wave & 1) * 64;
    int p15 = lane & 15, hi = lane >> 4;

    __shared__ unsigned short xs[6 * 34 * 64];   // 26112 B, [row][xx][ci']

    // stage 6 padded image rows (1632 uint4) via global_load_lds
    {
        const unsigned short* xsrc = xpad + (n * 34 + y0) * 2176;
#pragma unroll
        for (int pass = 0; pass < 7; ++pass) {
            int slot = pass * 256 + tid;
            if (slot < 1632)
                gld16(&xs[(pass * 256 + wave * 64) * 8], xsrc + slot * 8);
        }
    }
    __syncthreads();   // drains vmcnt; only barrier in the kernel

    f32x4 acc[4][4];
#pragma unroll
    for (int mf = 0; mf < 4; ++mf)
#pragma unroll
        for (int nf = 0; nf < 4; ++nf) acc[mf][nf] = (f32x4){0.f, 0.f, 0.f, 0.f};

    int yl[4], xb[4];
#pragma unroll
    for (int nf = 0; nf < 4; ++nf) {
        int posl = wn + nf * 16 + p15;
        yl[nf] = posl >> 5;
        xb[nf] = posl & 31;
    }

    // A base: twb element offset = tap*32768 + (hi + s*4)*4096 + (cot*128 + wm + mf*16 + p15)*8
    const unsigned short* abase = twb + hi * 4096 + (cot * 128 + wm + p15) * 8;

#pragma unroll
    for (int tap = 0; tap < 9; ++tap) {
        const int ky = tap / 3, kx = tap % 3;
        bf16x8 a[4][2], b[4][2];
#pragma unroll
        for (int s = 0; s < 2; ++s)
#pragma unroll
            for (int mf = 0; mf < 4; ++mf)
                a[mf][s] = *reinterpret_cast<const bf16x8*>(
                    abase + tap * 32768 + s * 16384 + mf * 128);
#pragma unroll
        for (int nf = 0; nf < 4; ++nf) {
            int row = yl[nf] + ky, col = xb[nf] + kx;
#pragma unroll
            for (int s = 0; s < 2; ++s) {
                int cig = hi + s * 4;
                b[nf][s] = *reinterpret_cast<const bf16x8*>(
                    &xs[(row * 34 + col) * 64 + ((cig ^ (col & 7)) << 3)]);
            }
        }
#pragma unroll
        for (int s = 0; s < 2; ++s)
#pragma unroll
            for (int mf = 0; mf < 4; ++mf)
#pragma unroll
                for (int nf = 0; nf < 4; ++nf)
                    acc[mf][nf] = __builtin_amdgcn_mfma_f32_16x16x32_bf16(
                        a[mf][s], b[nf][s], acc[mf][nf], 0, 0, 0);
    }

    // epilogue: write p + fused BN channel partial sums
#pragma unroll
    for (int mf = 0; mf < 4; ++mf) {
        float s = 0.f, s2 = 0.f;
#pragma unroll
        for (int nf = 0; nf < 4; ++nf) {
            int posl = wn + nf * 16 + p15;
            int y = y0 + (posl >> 5), x = posl & 31;
#pragma unroll
            for (int reg = 0; reg < 4; ++reg) {
                float v = acc[mf][nf][reg];
                s += v; s2 += v * v;
                int co4 = cot * 128 + wm + mf * 16 + hi * 4 + reg;
                p[((n * 512 + co4) * 32 + y) * 32 + x] = f2bf(v);
            }
        }
        // channel = co4>>2 = cot*32 + wm/4 + mf*4 + hi (independent of reg, nf)
        s  += __shfl_xor(s, 1);  s  += __shfl_xor(s, 2);  s  += __shfl_xor(s, 4);  s  += __shfl_xor(s, 8);
        s2 += __shfl_xor(s2, 1); s2 += __shfl_xor(s2, 2); s2 += __shfl_xor(s2, 4); s2 += __shfl_xor(s2, 8);
        if (p15 == 0) {
            int ch = cot * 32 + (wm >> 2) + mf * 4 + hi;
            atomicAdd(&ps[2 * ch], s);
            atomicAdd(&ps[2 * ch + 1], s2);
        }
    }
}

// ---------------- kernel 4: finalize affine coefs ----------------
__global__ __launch_bounds__(128) void k_ab(const float* __restrict__ ps,
                                            const float* __restrict__ gamma,
                                            const float* __restrict__ beta,
                                            float* __restrict__ ab) {
    int c = threadIdx.x;
    float S  = ps[2 * c];
    float S2 = ps[2 * c + 1];
    float mean = S * (1.f / 262144.f);
    float var = S2 * (1.f / 262144.f) - mean * mean;
    float A = gamma[c] * rsqrtf(var + 1e-5f);
    ab[2 * c] = A;
    ab[2 * c + 1] = beta[c] - mean * A;
}

// ---------------- kernel 5: fused routing + entropy ----------------
// grid 2048; bid: k=bid&7, ch=(bid>>3)&1, unit=(bid>>4)*8+k
// unit: b = u>>7, r = (u>>5)&3, y = u&31 ; chunk covers x0 = ch*16 .. +15
__global__ __launch_bounds__(256, 4) void k_route(const unsigned short* __restrict__ pp,
                                                  const float* __restrict__ ab,
                                                  float* __restrict__ out,
                                                  float* __restrict__ ent_out) {
    int bid = blockIdx.x;
    int u = ((bid >> 4) << 3) + (bid & 7);
    int ch = (bid >> 3) & 1;
    int y = u & 31, r = (u >> 5) & 3, b = u >> 7;
    int x0 = ch * 16;
    int tid = threadIdx.x;
    int wave = tid >> 6, lane = tid & 63;
    int i_l = lane >> 3, oc_l = lane & 7;

    __shared__ unsigned int Tl2[16][8][64];      // [od][x-pair][lane(i,oc)]  32 KB
    __shared__ unsigned short vst[8][16][18];    // [oc][od][x+pad]           4.5 KB
    __shared__ float ered[4];

#pragma unroll
    for (int t4i = 0; t4i < 4; ++t4i) {
        int t4 = tid + t4i * 256;
        int od = t4 >> 6, ls = t4 & 63;
        int ii = ls >> 3, oo = ls & 7;
        int c = oo * 16 + od;
        int co4 = c * 4 + r;
        int n = b * 8 + ii;
        float A = ab[2 * c], Bv = ab[2 * c + 1];
        const uint4* src = reinterpret_cast<const uint4*>(pp + ((n * 512 + co4) * 32 + y) * 32 + x0);
        uint4 d0 = src[0], d1 = src[1];
        unsigned wds[8] = {d0.x, d0.y, d0.z, d0.w, d1.x, d1.y, d1.z, d1.w};
#pragma unroll
        for (int j = 0; j < 8; ++j) {
            float tlo = A * bf2f(wds[j] & 0xffffu) + Bv;
            float thi = A * bf2f(wds[j] >> 16) + Bv;
            Tl2[od][j][ls] = (unsigned)f2bf(tlo) | ((unsigned)f2bf(thi) << 16);
        }
    }
    __syncthreads();

    float e_acc = 0.f;

    for (int q = 0; q < 2; ++q) {
        int p2 = wave + q * 4;
        float t0[16], t1[16];
#pragma unroll
        for (int od = 0; od < 16; ++od) {
            unsigned pr = Tl2[od][p2][lane];
            t0[od] = bf2f(pr & 0xffffu);
            t1[od] = bf2f(pr >> 16);
        }

        float b0 = 0.f, b1 = 0.f, c0, c1, sc0 = 0.f, sc1 = 0.f;
        float s0[16], s1[16];
        for (int it = 0; it < 3; ++it) {
            float m0 = b0, m1 = b1;
            m0 = fmaxf(m0, dppx1(m0));      m1 = fmaxf(m1, dppx1(m1));
            m0 = fmaxf(m0, dppx2(m0));      m1 = fmaxf(m1, dppx2(m1));
            m0 = fmaxf(m0, swzf<SWZ4>(m0)); m1 = fmaxf(m1, swzf<SWZ4>(m1));
            float e0 = __expf(b0 - m0), e1 = __expf(b1 - m1);
            float se0 = e0, se1 = e1;
            se0 += dppx1(se0);      se1 += dppx1(se1);
            se0 += dppx2(se0);      se1 += dppx2(se1);
            se0 += swzf<SWZ4>(se0); se1 += swzf<SWZ4>(se1);
            c0 = e0 * __builtin_amdgcn_rcpf(se0);
            c1 = e1 * __builtin_amdgcn_rcpf(se1);
            float n20 = 0.f, n21 = 0.f;
#pragma unroll
            for (int od = 0; od < 16; ++od) {
                float v0 = c0 * t0[od], v1 = c1 * t1[od];
                v0 += swzf<SWZ8>(v0);   v1 += swzf<SWZ8>(v1);
                v0 += swzf<SWZ16>(v0);  v1 += swzf<SWZ16>(v1);
                v0 = psum32(v0);        v1 = psum32(v1);
                s0[od] = v0;            s1[od] = v1;
                n20 += v0 * v0;         n21 += v1 * v1;
            }
            float nr0 = sqrtf(n20), nr1 = sqrtf(n21);
            sc0 = n20 * __builtin_amdgcn_rcpf((1.f + n20) * (nr0 + 1e-8f));
            sc1 = n21 * __builtin_amdgcn_rcpf((1.f + n21) * (nr1 + 1e-8f));
            if (it < 2) {
                float a0 = 0.f, a1 = 0.f;
#pragma unroll
                for (int od = 0; od < 16; ++od) {
                    a0 += t0[od] * s0[od];
                    a1 += t1[od] * s1[od];
                }
                b0 += a0 * sc0;
                b1 += a1 * sc1;
            }
        }
        e_acc += -c0 * __logf(c0) - c1 * __logf(c1);
        if (i_l == 0) {
#pragma unroll
            for (int od = 0; od < 16; ++od) {
                vst[oc_l][od][2 * p2]     = f2bf(sc0 * s0[od]);
                vst[oc_l][od][2 * p2 + 1] = f2bf(sc1 * s1[od]);
            }
        }
    }

    e_acc += dppx1(e_acc);
    e_acc += dppx2(e_acc);
    e_acc += swzf<SWZ4>(e_acc);
    e_acc += swzf<SWZ8>(e_acc);
    e_acc += swzf<SWZ16>(e_acc);
    e_acc = psum32(e_acc);
    if (lane == 0) ered[wave] = e_acc;
    __syncthreads();

    {
        int xx = tid & 15, od = (tid >> 4) & 15;
#pragma unroll
        for (int oc = 0; oc < 8; ++oc) {
            out[((((b * 8 + oc) * 16 + od) * 4 + r) * 32 + y) * 32 + x0 + xx] =
                bf2f(vst[oc][od][xx]);
        }
    }
    if (tid == 0) {
        float tot = ered[0] + ered[1] + ered[2] + ered[3];
        atomicAdd(ent_out, tot * (1.0f / (2.0794415416798357f * 32768.0f)));
    }
}

extern "C" void kernel_launch(void* const* d_in, const int* in_sizes, int n_in,
                              void* d_out, int out_size, void* d_ws, size_t ws_size,
                              hipStream_t stream) {
    const float* x     = (const float*)d_in[0];  // (8,8,16,4,32,32)
    const float* w     = (const float*)d_in[1];  // (128,16,4,3,3)
    const float* gamma = (const float*)d_in[2];  // (128)
    const float* beta  = (const float*)d_in[3];  // (128)
    float* out = (float*)d_out;                  // 4,194,304 v + 1 entropy

    char* ws = (char*)d_ws;
    unsigned short* p    = (unsigned short*)ws;                                  // 67,108,864 B
    unsigned short* xpad = (unsigned short*)(ws + 67108864);                     //  9,469,952 B
    unsigned short* twb  = (unsigned short*)(ws + 67108864 + 9469952);           //    589,824 B
    float* ab            = (float*)(ws + 67108864 + 9469952 + 589824);           //      1,024 B
    float* ps            = (float*)(ws + 67108864 + 9469952 + 589824 + 1024);    //      1,024 B

    hipMemsetAsync(out + 4194304, 0, 4, stream);
    hipMemsetAsync(xpad, 0, 9469952, stream);
    hipMemsetAsync(ps, 0, 1024, stream);

    k_twb<<<1152, 256, 0, stream>>>(w, twb);
    k_prep<<<2048, 256, 0, stream>>>(x, xpad);

    dim3 gconv(64, 8, 4);
    k_mconv<<<gconv, 256, 0, stream>>>(xpad, twb, p, ps);

    k_ab<<<1, 128, 0, stream>>>(ps, gamma, beta, ab);

    k_route<<<2048, 256, 0, stream>>>(p, ab, out, out + 4194304);
}

// Round 8
// 272.038 us; speedup vs baseline: 1.0200x; 1.0200x over previous
//
#include <hip/hip_runtime.h>
#include <hip/hip_bf16.h>

// B=8 IC=8 ID=16 OC=8 OD=16 H=W=32 K=3 ITER=3
// conv as MFMA GEMM per image: A=tw (512 co4 x 576 k), B=im2col(x) (576 k x 1024 pos)
// p (64, 512, 32, 32) bf16.  Routing per (b, r, y, x).
// v output: (B, OC, OD, 4, H, W) = 4,194,304 fp32; entropy scalar at out[4194304]

typedef short bf16x8 __attribute__((ext_vector_type(8)));
typedef float f32x4 __attribute__((ext_vector_type(4)));
typedef unsigned int u32x2 __attribute__((ext_vector_type(2)));

__device__ inline float bf2f(unsigned int u) {
    union { unsigned int i; float f; } x;
    x.i = u << 16;
    return x.f;
}
__device__ inline unsigned short f2bf(float f) {
    union { float f; unsigned int u; } x;
    x.f = f;
    unsigned int r = x.u + 0x7fffu + ((x.u >> 16) & 1u);
    return (unsigned short)(r >> 16);
}

// async global->LDS 16B per lane: LDS dest = wave-uniform base + lane*16
__device__ __forceinline__ void gld16(void* lds_uniform, const void* gsrc) {
    __builtin_amdgcn_global_load_lds(
        (const __attribute__((address_space(1))) unsigned int*)gsrc,
        (__attribute__((address_space(3))) unsigned int*)lds_uniform,
        16, 0, 0);
}

// cross-lane helpers (all-lanes-active contexts only)
__device__ inline float dppx1(float x) {
    return __int_as_float(__builtin_amdgcn_update_dpp(0, __float_as_int(x), 0xB1, 0xF, 0xF, false));
}
__device__ inline float dppx2(float x) {
    return __int_as_float(__builtin_amdgcn_update_dpp(0, __float_as_int(x), 0x4E, 0xF, 0xF, false));
}
template <int PATT>
__device__ inline float swzf(float x) {
    return __int_as_float(__builtin_amdgcn_ds_swizzle(__float_as_int(x), PATT));
}
#define SWZ4  0x101F
#define SWZ8  0x201F
#define SWZ16 0x401F
__device__ inline float psum32(float x) {  // x + x[lane^32]
    u32x2 r = __builtin_amdgcn_permlane32_swap(__float_as_uint(x), __float_as_uint(x), false, false);
    return __uint_as_float(r[0]) + __uint_as_float(r[1]);
}

// ---------------- kernel 1: transformed weights, bf16, pre-swizzled ----------------
// twb[tap][co4][ci'] : [9][512][64] bf16 ; stored ci' = ci ^ ((co4&7)<<3)
__global__ __launch_bounds__(256) void k_twb(const float* __restrict__ w,
                                             unsigned short* __restrict__ twb) {
    int idx = blockIdx.x * 256 + threadIdx.x;
    int tap = idx >> 15;
    int rem = idx & 32767;
    int co4 = rem >> 6;
    int cst = rem & 63;
    int ci = cst ^ ((co4 & 7) << 3);
    int r = co4 & 3, co = co4 >> 2;
    int s = ci & 3, cicap = ci >> 2;
    int ky = tap / 3, kx = tap % 3;
    int sy, sx;
    switch (r) {
        case 0: sy = ky;      sx = kx;      break;
        case 1: sy = kx;      sx = 2 - ky;  break;
        case 2: sy = 2 - ky;  sx = 2 - kx;  break;
        default: sy = 2 - kx; sx = ky;      break;
    }
    int ss = (s - r) & 3;
    twb[idx] = f2bf(w[(((co * 16 + cicap) * 4 + ss) * 3 + sy) * 3 + sx]);
}

// ---------------- kernel 2: pad + transpose + bf16 + swizzle the input ----------------
// xpad[n][yy][xx][ci'] : [64][34][34][64] bf16 ; ci' = ci ^ ((xx&7)<<3); borders pre-zeroed
__global__ __launch_bounds__(256) void k_prep(const float* __restrict__ xf,
                                              unsigned short* __restrict__ xpad) {
    int n = blockIdx.x >> 5, y = blockIdx.x & 31;
    int tid = threadIdx.x;
    __shared__ float tile[64][33];
#pragma unroll
    for (int it = 0; it < 8; ++it) {
        int ci = it * 8 + (tid >> 5), x = tid & 31;
        tile[ci][x] = xf[((n * 64 + ci) * 32 + y) * 32 + x];
    }
    __syncthreads();
    int xx = 1 + (tid >> 3), g = tid & 7;
    int x = xx - 1;
    int lg = g ^ (xx & 7);
    unsigned short vals[8];
#pragma unroll
    for (int j = 0; j < 8; ++j) vals[j] = f2bf(tile[lg * 8 + j][x]);
    uint4 pk;
    pk.x = (unsigned)vals[0] | ((unsigned)vals[1] << 16);
    pk.y = (unsigned)vals[2] | ((unsigned)vals[3] << 16);
    pk.z = (unsigned)vals[4] | ((unsigned)vals[5] << 16);
    pk.w = (unsigned)vals[6] | ((unsigned)vals[7] << 16);
    *reinterpret_cast<uint4*>(&xpad[(n * 34 + (y + 1)) * 2176 + xx * 64 + g * 8]) = pk;
}

// ---------------- kernel 3: MFMA conv + fused BN partial stats ----------------
// grid (64 n, 8 yt, 4 cot), 256 threads = 4 waves in 2x2
// wave tile: 64 co4 x 64 pos (4x4 frags 16x16), K = 9 taps x 2 steps of 32
// Per tap: a-reads -> barrier -> async gld16(tap+1 into wA) -> b-reads+MFMA -> barrier(drain)
__global__ __launch_bounds__(256, 3) void k_mconv(const unsigned short* __restrict__ xpad,
                                                  const unsigned short* __restrict__ twb,
                                                  unsigned short* __restrict__ p,
                                                  float* __restrict__ ps) {
    int n = blockIdx.x, yt = blockIdx.y, cot = blockIdx.z;
    int y0 = yt * 4;
    int tid = threadIdx.x, lane = tid & 63, wave = tid >> 6;
    int wm = (wave >> 1) * 64, wn = (wave & 1) * 64;
    int p15 = lane & 15, hi = lane >> 4;

    __shared__ unsigned short xs[6 * 34 * 64];   // 26112 B, [row][xx][ci']
    __shared__ unsigned short wA[128 * 64];      // 16384 B, [co4l][ci']

    // ---- prologue: async-stage xs (1632 uint4) and wA tap0 (1024 uint4) ----
    {
        const unsigned short* xsrc = xpad + (n * 34 + y0) * 2176;
#pragma unroll
        for (int pass = 0; pass < 7; ++pass) {
            int slot = pass * 256 + tid;
            if (slot < 1632)
                gld16(&xs[(pass * 256 + wave * 64) * 8], xsrc + slot * 8);
        }
        const unsigned short* wsrc = twb + (cot * 128) * 64;
#pragma unroll
        for (int pass = 0; pass < 4; ++pass)
            gld16(&wA[(pass * 256 + wave * 64) * 8], wsrc + (pass * 256 + tid) * 8);
    }
    __syncthreads();   // drains vmcnt; xs + wA(tap0) ready

    f32x4 acc[4][4];
#pragma unroll
    for (int mf = 0; mf < 4; ++mf)
#pragma unroll
        for (int nf = 0; nf < 4; ++nf) acc[mf][nf] = (f32x4){0.f, 0.f, 0.f, 0.f};

    int yl[4], xb[4];
#pragma unroll
    for (int nf = 0; nf < 4; ++nf) {
        int posl = wn + nf * 16 + p15;
        yl[nf] = posl >> 5;
        xb[nf] = posl & 31;
    }

#pragma unroll
    for (int tap = 0; tap < 9; ++tap) {
        const int ky = tap / 3, kx = tap % 3;

        // 1. read this tap's A-fragments into registers
        bf16x8 a[4][2];
#pragma unroll
        for (int mf = 0; mf < 4; ++mf) {
            int co4l = wm + mf * 16 + p15;
#pragma unroll
            for (int s = 0; s < 2; ++s) {
                int cig = hi + s * 4;
                a[mf][s] = *reinterpret_cast<const bf16x8*>(
                    &wA[co4l * 64 + ((cig ^ (co4l & 7)) << 3)]);
            }
        }
        // 2. all waves have consumed wA
        __syncthreads();
        // 3. async-issue next tap's weights into the (now dead) wA buffer
        if (tap < 8) {
            const unsigned short* wsrc = twb + ((tap + 1) * 512 + cot * 128) * 64;
#pragma unroll
            for (int pass = 0; pass < 4; ++pass)
                gld16(&wA[(pass * 256 + wave * 64) * 8], wsrc + (pass * 256 + tid) * 8);
        }
        // 4. b-reads + MFMA (no wA dependence) hide the load latency
        bf16x8 b[4][2];
#pragma unroll
        for (int nf = 0; nf < 4; ++nf) {
            int row = yl[nf] + ky, col = xb[nf] + kx;
#pragma unroll
            for (int s = 0; s < 2; ++s) {
                int cig = hi + s * 4;
                b[nf][s] = *reinterpret_cast<const bf16x8*>(
                    &xs[(row * 34 + col) * 64 + ((cig ^ (col & 7)) << 3)]);
            }
        }
#pragma unroll
        for (int s = 0; s < 2; ++s)
#pragma unroll
            for (int mf = 0; mf < 4; ++mf)
#pragma unroll
                for (int nf = 0; nf < 4; ++nf)
                    acc[mf][nf] = __builtin_amdgcn_mfma_f32_16x16x32_bf16(
                        a[mf][s], b[nf][s], acc[mf][nf], 0, 0, 0);
        // 5. drain gld16s (vmcnt(0) before barrier) -> wA holds tap+1
        if (tap < 8) __syncthreads();
    }

    // ---- epilogue: write p + fused BN channel partial sums ----
#pragma unroll
    for (int mf = 0; mf < 4; ++mf) {
        float s = 0.f, s2 = 0.f;
#pragma unroll
        for (int nf = 0; nf < 4; ++nf) {
            int posl = wn + nf * 16 + p15;
            int y = y0 + (posl >> 5), x = posl & 31;
#pragma unroll
            for (int reg = 0; reg < 4; ++reg) {
                float v = acc[mf][nf][reg];
                s += v; s2 += v * v;
                int co4 = cot * 128 + wm + mf * 16 + hi * 4 + reg;
                p[((n * 512 + co4) * 32 + y) * 32 + x] = f2bf(v);
            }
        }
        // channel = co4>>2 = cot*32 + wm/4 + mf*4 + hi (independent of reg, nf)
        s  += __shfl_xor(s, 1);  s  += __shfl_xor(s, 2);  s  += __shfl_xor(s, 4);  s  += __shfl_xor(s, 8);
        s2 += __shfl_xor(s2, 1); s2 += __shfl_xor(s2, 2); s2 += __shfl_xor(s2, 4); s2 += __shfl_xor(s2, 8);
        if (p15 == 0) {
            int ch = cot * 32 + (wm >> 2) + mf * 4 + hi;
            atomicAdd(&ps[2 * ch], s);
            atomicAdd(&ps[2 * ch + 1], s2);
        }
    }
}

// ---------------- kernel 4: finalize affine coefs ----------------
__global__ __launch_bounds__(128) void k_ab(const float* __restrict__ ps,
                                            const float* __restrict__ gamma,
                                            const float* __restrict__ beta,
                                            float* __restrict__ ab) {
    int c = threadIdx.x;
    float S  = ps[2 * c];
    float S2 = ps[2 * c + 1];
    float mean = S * (1.f / 262144.f);
    float var = S2 * (1.f / 262144.f) - mean * mean;
    float A = gamma[c] * rsqrtf(var + 1e-5f);
    ab[2 * c] = A;
    ab[2 * c + 1] = beta[c] - mean * A;
}

// ---------------- kernel 5: fused routing + entropy ----------------
// grid 2048; bid: k=bid&7, ch=(bid>>3)&1, unit=(bid>>4)*8+k
// unit: b = u>>7, r = (u>>5)&3, y = u&31 ; chunk covers x0 = ch*16 .. +15
__global__ __launch_bounds__(256, 4) void k_route(const unsigned short* __restrict__ pp,
                                                  const float* __restrict__ ab,
                                                  float* __restrict__ out,
                                                  float* __restrict__ ent_out) {
    int bid = blockIdx.x;
    int u = ((bid >> 4) << 3) + (bid & 7);
    int ch = (bid >> 3) & 1;
    int y = u & 31, r = (u >> 5) & 3, b = u >> 7;
    int x0 = ch * 16;
    int tid = threadIdx.x;
    int wave = tid >> 6, lane = tid & 63;
    int i_l = lane >> 3, oc_l = lane & 7;

    __shared__ unsigned int Tl2[16][8][64];      // [od][x-pair][lane(i,oc)]  32 KB
    __shared__ unsigned short vst[8][16][18];    // [oc][od][x+pad]           4.5 KB
    __shared__ float ered[4];

#pragma unroll
    for (int t4i = 0; t4i < 4; ++t4i) {
        int t4 = tid + t4i * 256;
        int od = t4 >> 6, ls = t4 & 63;
        int ii = ls >> 3, oo = ls & 7;
        int c = oo * 16 + od;
        int co4 = c * 4 + r;
        int n = b * 8 + ii;
        float A = ab[2 * c], Bv = ab[2 * c + 1];
        const uint4* src = reinterpret_cast<const uint4*>(pp + ((n * 512 + co4) * 32 + y) * 32 + x0);
        uint4 d0 = src[0], d1 = src[1];
        unsigned wds[8] = {d0.x, d0.y, d0.z, d0.w, d1.x, d1.y, d1.z, d1.w};
#pragma unroll
        for (int j = 0; j < 8; ++j) {
            float tlo = A * bf2f(wds[j] & 0xffffu) + Bv;
            float thi = A * bf2f(wds[j] >> 16) + Bv;
            Tl2[od][j][ls] = (unsigned)f2bf(tlo) | ((unsigned)f2bf(thi) << 16);
        }
    }
    __syncthreads();

    float e_acc = 0.f;

    for (int q = 0; q < 2; ++q) {
        int p2 = wave + q * 4;
        float t0[16], t1[16];
#pragma unroll
        for (int od = 0; od < 16; ++od) {
            unsigned pr = Tl2[od][p2][lane];
            t0[od] = bf2f(pr & 0xffffu);
            t1[od] = bf2f(pr >> 16);
        }

        float b0 = 0.f, b1 = 0.f, c0, c1, sc0 = 0.f, sc1 = 0.f;
        float s0[16], s1[16];
        for (int it = 0; it < 3; ++it) {
            float m0 = b0, m1 = b1;
            m0 = fmaxf(m0, dppx1(m0));      m1 = fmaxf(m1, dppx1(m1));
            m0 = fmaxf(m0, dppx2(m0));      m1 = fmaxf(m1, dppx2(m1));
            m0 = fmaxf(m0, swzf<SWZ4>(m0)); m1 = fmaxf(m1, swzf<SWZ4>(m1));
            float e0 = __expf(b0 - m0), e1 = __expf(b1 - m1);
            float se0 = e0, se1 = e1;
            se0 += dppx1(se0);      se1 += dppx1(se1);
            se0 += dppx2(se0);      se1 += dppx2(se1);
            se0 += swzf<SWZ4>(se0); se1 += swzf<SWZ4>(se1);
            c0 = e0 * __builtin_amdgcn_rcpf(se0);
            c1 = e1 * __builtin_amdgcn_rcpf(se1);
            float n20 = 0.f, n21 = 0.f;
#pragma unroll
            for (int od = 0; od < 16; ++od) {
                float v0 = c0 * t0[od], v1 = c1 * t1[od];
                v0 += swzf<SWZ8>(v0);   v1 += swzf<SWZ8>(v1);
                v0 += swzf<SWZ16>(v0);  v1 += swzf<SWZ16>(v1);
                v0 = psum32(v0);        v1 = psum32(v1);
                s0[od] = v0;            s1[od] = v1;
                n20 += v0 * v0;         n21 += v1 * v1;
            }
            float nr0 = sqrtf(n20), nr1 = sqrtf(n21);
            sc0 = n20 * __builtin_amdgcn_rcpf((1.f + n20) * (nr0 + 1e-8f));
            sc1 = n21 * __builtin_amdgcn_rcpf((1.f + n21) * (nr1 + 1e-8f));
            if (it < 2) {
                float a0 = 0.f, a1 = 0.f;
#pragma unroll
                for (int od = 0; od < 16; ++od) {
                    a0 += t0[od] * s0[od];
                    a1 += t1[od] * s1[od];
                }
                b0 += a0 * sc0;
                b1 += a1 * sc1;
            }
        }
        e_acc += -c0 * __logf(c0) - c1 * __logf(c1);
        if (i_l == 0) {
#pragma unroll
            for (int od = 0; od < 16; ++od) {
                vst[oc_l][od][2 * p2]     = f2bf(sc0 * s0[od]);
                vst[oc_l][od][2 * p2 + 1] = f2bf(sc1 * s1[od]);
            }
        }
    }

    e_acc += dppx1(e_acc);
    e_acc += dppx2(e_acc);
    e_acc += swzf<SWZ4>(e_acc);
    e_acc += swzf<SWZ8>(e_acc);
    e_acc += swzf<SWZ16>(e_acc);
    e_acc = psum32(e_acc);
    if (lane == 0) ered[wave] = e_acc;
    __syncthreads();

    {
        int xx = tid & 15, od = (tid >> 4) & 15;
#pragma unroll
        for (int oc = 0; oc < 8; ++oc) {
            out[((((b * 8 + oc) * 16 + od) * 4 + r) * 32 + y) * 32 + x0 + xx] =
                bf2f(vst[oc][od][xx]);
        }
    }
    if (tid == 0) {
        float tot = ered[0] + ered[1] + ered[2] + ered[3];
        atomicAdd(ent_out, tot * (1.0f / (2.0794415416798357f * 32768.0f)));
    }
}

extern "C" void kernel_launch(void* const* d_in, const int* in_sizes, int n_in,
                              void* d_out, int out_size, void* d_ws, size_t ws_size,
                              hipStream_t stream) {
    const float* x     = (const float*)d_in[0];  // (8,8,16,4,32,32)
    const float* w     = (const float*)d_in[1];  // (128,16,4,3,3)
    const float* gamma = (const float*)d_in[2];  // (128)
    const float* beta  = (const float*)d_in[3];  // (128)
    float* out = (float*)d_out;                  // 4,194,304 v + 1 entropy

    char* ws = (char*)d_ws;
    unsigned short* p    = (unsigned short*)ws;                                  // 67,108,864 B
    unsigned short* xpad = (unsigned short*)(ws + 67108864);                     //  9,469,952 B
    unsigned short* twb  = (unsigned short*)(ws + 67108864 + 9469952);           //    589,824 B
    float* ab            = (float*)(ws + 67108864 + 9469952 + 589824);           //      1,024 B
    float* ps            = (float*)(ws + 67108864 + 9469952 + 589824 + 1024);    //      1,024 B

    hipMemsetAsync(out + 4194304, 0, 4, stream);
    hipMemsetAsync(xpad, 0, 9469952, stream);
    hipMemsetAsync(ps, 0, 1024, stream);

    k_twb<<<1152, 256, 0, stream>>>(w, twb);
    k_prep<<<2048, 256, 0, stream>>>(x, xpad);

    dim3 gconv(64, 8, 4);
    k_mconv<<<gconv, 256, 0, stream>>>(xpad, twb, p, ps);

    k_ab<<<1, 128, 0, stream>>>(ps, gamma, beta, ab);

    k_route<<<2048, 256, 0, stream>>>(p, ab, out, out + 4194304);
}

// Round 9
// 183.651 us; speedup vs baseline: 1.5108x; 1.4813x over previous
//
#include <hip/hip_runtime.h>
#include <hip/hip_bf16.h>

// B=8 IC=8 ID=16 OC=8 OD=16 H=W=32 K=3 ITER=3
// conv as MFMA GEMM per image: A=tw (512 co4 x 576 k), B=im2col(x) (576 k x 1024 pos)
// p (64, 512, 32, 32) bf16.  Routing per (b, r, y, x).
// v output: (B, OC, OD, 4, H, W) = 4,194,304 fp32; entropy scalar at out[4194304]

typedef short bf16x8 __attribute__((ext_vector_type(8)));
typedef float f32x4 __attribute__((ext_vector_type(4)));
typedef unsigned int u32x2 __attribute__((ext_vector_type(2)));

__device__ inline float bf2f(unsigned int u) {
    union { unsigned int i; float f; } x;
    x.i = u << 16;
    return x.f;
}
__device__ inline unsigned short f2bf(float f) {
    union { float f; unsigned int u; } x;
    x.f = f;
    unsigned int r = x.u + 0x7fffu + ((x.u >> 16) & 1u);
    return (unsigned short)(r >> 16);
}

// cross-lane helpers (all-lanes-active contexts only)
__device__ inline float dppx1(float x) {
    return __int_as_float(__builtin_amdgcn_update_dpp(0, __float_as_int(x), 0xB1, 0xF, 0xF, false));
}
__device__ inline float dppx2(float x) {
    return __int_as_float(__builtin_amdgcn_update_dpp(0, __float_as_int(x), 0x4E, 0xF, 0xF, false));
}
template <int PATT>
__device__ inline float swzf(float x) {
    return __int_as_float(__builtin_amdgcn_ds_swizzle(__float_as_int(x), PATT));
}
#define SWZ4  0x101F
#define SWZ8  0x201F
#define SWZ16 0x401F
__device__ inline float psum32(float x) {  // x + x[lane^32]
    u32x2 r = __builtin_amdgcn_permlane32_swap(__float_as_uint(x), __float_as_uint(x), false, false);
    return __uint_as_float(r[0]) + __uint_as_float(r[1]);
}

// ---------------- kernel 1: transformed weights, bf16, pre-swizzled ----------------
// twb[tap][co4][ci'] : [9][512][64] bf16 ; stored ci' = ci ^ ((co4&7)<<3)
__global__ __launch_bounds__(256) void k_twb(const float* __restrict__ w,
                                             unsigned short* __restrict__ twb) {
    int idx = blockIdx.x * 256 + threadIdx.x;
    int tap = idx >> 15;
    int rem = idx & 32767;
    int co4 = rem >> 6;
    int cst = rem & 63;
    int ci = cst ^ ((co4 & 7) << 3);
    int r = co4 & 3, co = co4 >> 2;
    int s = ci & 3, cicap = ci >> 2;
    int ky = tap / 3, kx = tap % 3;
    int sy, sx;
    switch (r) {
        case 0: sy = ky;      sx = kx;      break;
        case 1: sy = kx;      sx = 2 - ky;  break;
        case 2: sy = 2 - ky;  sx = 2 - kx;  break;
        default: sy = 2 - kx; sx = ky;      break;
    }
    int ss = (s - r) & 3;
    twb[idx] = f2bf(w[(((co * 16 + cicap) * 4 + ss) * 3 + sy) * 3 + sx]);
}

// ---------------- kernel 2: pad + transpose + bf16 + swizzle the input ----------------
// xpad[n][yy][xx][ci'] : [64][34][34][64] bf16 ; ci' = ci ^ ((xx&7)<<3); borders pre-zeroed
__global__ __launch_bounds__(256) void k_prep(const float* __restrict__ xf,
                                              unsigned short* __restrict__ xpad) {
    int n = blockIdx.x >> 5, y = blockIdx.x & 31;
    int tid = threadIdx.x;
    __shared__ float tile[64][33];
#pragma unroll
    for (int it = 0; it < 8; ++it) {
        int ci = it * 8 + (tid >> 5), x = tid & 31;
        tile[ci][x] = xf[((n * 64 + ci) * 32 + y) * 32 + x];
    }
    __syncthreads();
    int xx = 1 + (tid >> 3), g = tid & 7;
    int x = xx - 1;
    int lg = g ^ (xx & 7);
    unsigned short vals[8];
#pragma unroll
    for (int j = 0; j < 8; ++j) vals[j] = f2bf(tile[lg * 8 + j][x]);
    uint4 pk;
    pk.x = (unsigned)vals[0] | ((unsigned)vals[1] << 16);
    pk.y = (unsigned)vals[2] | ((unsigned)vals[3] << 16);
    pk.z = (unsigned)vals[4] | ((unsigned)vals[5] << 16);
    pk.w = (unsigned)vals[6] | ((unsigned)vals[7] << 16);
    *reinterpret_cast<uint4*>(&xpad[(n * 34 + (y + 1)) * 2176 + xx * 64 + g * 8]) = pk;
}

// ---------------- kernel 3: MFMA conv, reg-staged pipelined weights ----------------
// grid (64 n, 8 yt, 4 cot), 256 threads = 4 waves in 2x2
// wave tile: 64 co4 x 64 pos (4x4 frags 16x16), K = 9 taps x 2 steps of 32
// Per tap: a-reads -> barrierA -> ds_write wA(tap+1 from regs) + issue loads(tap+2)
//          -> b-reads + 32 MFMA (covers load latency) -> barrierB
__global__ __launch_bounds__(256, 3) void k_mconv(const unsigned short* __restrict__ xpad,
                                                  const unsigned short* __restrict__ twb,
                                                  unsigned short* __restrict__ p) {
    int n = blockIdx.x, yt = blockIdx.y, cot = blockIdx.z;
    int y0 = yt * 4;
    int tid = threadIdx.x, lane = tid & 63, wave = tid >> 6;
    int wm = (wave >> 1) * 64, wn = (wave & 1) * 64;
    int p15 = lane & 15, hi = lane >> 4;

    __shared__ unsigned short xs[6 * 34 * 64];   // 26112 B, [row][xx][ci']
    __shared__ unsigned short wA[128 * 64];      // 16384 B, [co4l][ci']

    // ---- prologue ----
    {
        const uint4* src = reinterpret_cast<const uint4*>(xpad + (n * 34 + y0) * 2176);
        uint4* dst = reinterpret_cast<uint4*>(xs);
        for (int t = tid; t < 1632; t += 256) dst[t] = src[t];
        const uint4* w0 = reinterpret_cast<const uint4*>(twb + (cot * 128) * 64);
        uint4* wdst = reinterpret_cast<uint4*>(wA);
#pragma unroll
        for (int k = 0; k < 4; ++k) wdst[tid + k * 256] = w0[tid + k * 256];
    }
    // preload tap-1 weights into regs (consumed at tap 0's staging slot)
    uint4 wreg[4];
    {
        const uint4* w1 = reinterpret_cast<const uint4*>(twb + (512 + cot * 128) * 64);
#pragma unroll
        for (int k = 0; k < 4; ++k) wreg[k] = w1[tid + k * 256];
    }
    __syncthreads();

    f32x4 acc[4][4];
#pragma unroll
    for (int mf = 0; mf < 4; ++mf)
#pragma unroll
        for (int nf = 0; nf < 4; ++nf) acc[mf][nf] = (f32x4){0.f, 0.f, 0.f, 0.f};

    int yl[4], xb[4];
#pragma unroll
    for (int nf = 0; nf < 4; ++nf) {
        int posl = wn + nf * 16 + p15;
        yl[nf] = posl >> 5;
        xb[nf] = posl & 31;
    }

    for (int tap = 0; tap < 9; ++tap) {
        const int ky = tap / 3, kx = tap % 3;

        // 1. read this tap's A-fragments into registers
        bf16x8 a[4][2];
#pragma unroll
        for (int mf = 0; mf < 4; ++mf) {
            int co4l = wm + mf * 16 + p15;
#pragma unroll
            for (int s = 0; s < 2; ++s) {
                int cig = hi + s * 4;
                a[mf][s] = *reinterpret_cast<const bf16x8*>(
                    &wA[co4l * 64 + ((cig ^ (co4l & 7)) << 3)]);
            }
        }
        // 2. barrier A: all waves consumed wA; no vmem pending (wreg consumed last tap)
        __syncthreads();
        // 3. write tap+1 weights from regs, then issue loads for tap+2
        if (tap < 8) {
            uint4* wdst = reinterpret_cast<uint4*>(wA);
#pragma unroll
            for (int k = 0; k < 4; ++k) wdst[tid + k * 256] = wreg[k];
            if (tap < 7) {
                const uint4* wsrc = reinterpret_cast<const uint4*>(
                    twb + ((tap + 2) * 512 + cot * 128) * 64);
#pragma unroll
                for (int k = 0; k < 4; ++k) wreg[k] = wsrc[tid + k * 256];
            }
        }
        // 4. b-reads + MFMA (hide the just-issued load latency)
        bf16x8 b[4][2];
#pragma unroll
        for (int nf = 0; nf < 4; ++nf) {
            int row = yl[nf] + ky, col = xb[nf] + kx;
#pragma unroll
            for (int s = 0; s < 2; ++s) {
                int cig = hi + s * 4;
                b[nf][s] = *reinterpret_cast<const bf16x8*>(
                    &xs[(row * 34 + col) * 64 + ((cig ^ (col & 7)) << 3)]);
            }
        }
#pragma unroll
        for (int s = 0; s < 2; ++s)
#pragma unroll
            for (int mf = 0; mf < 4; ++mf)
#pragma unroll
                for (int nf = 0; nf < 4; ++nf)
                    acc[mf][nf] = __builtin_amdgcn_mfma_f32_16x16x32_bf16(
                        a[mf][s], b[nf][s], acc[mf][nf], 0, 0, 0);
        // 5. barrier B: wA(tap+1) visible for next a-reads
        if (tap < 8) __syncthreads();
    }

    // ---- epilogue: write p ----
#pragma unroll
    for (int mf = 0; mf < 4; ++mf)
#pragma unroll
        for (int nf = 0; nf < 4; ++nf) {
            int posl = wn + nf * 16 + p15;
            int y = y0 + (posl >> 5), x = posl & 31;
#pragma unroll
            for (int reg = 0; reg < 4; ++reg) {
                int co4 = cot * 128 + wm + mf * 16 + hi * 4 + reg;
                p[((n * 512 + co4) * 32 + y) * 32 + x] = f2bf(acc[mf][nf][reg]);
            }
        }
}

// ---------------- kernel 4a: BN partial sums (512 blocks) ----------------
__global__ __launch_bounds__(256) void k_stats1(const unsigned short* __restrict__ pp,
                                                float* __restrict__ ps) {
    int c = blockIdx.x >> 2, q = blockIdx.x & 3;
    int tid = threadIdx.x;
    float s = 0.f, s2 = 0.f;
    for (int t = tid; t < 8192; t += 256) {
        int idx8 = t << 3;
        int nn = (q << 4) + (idx8 >> 12);
        int rem = idx8 & 4095;
        int co4 = (c << 2) + (rem >> 10);
        int pos = rem & 1023;
        uint4 d = *reinterpret_cast<const uint4*>(pp + (((nn << 9) + co4) << 10) + pos);
        float f;
        f = bf2f(d.x & 0xffffu); s += f; s2 += f * f;
        f = bf2f(d.x >> 16);     s += f; s2 += f * f;
        f = bf2f(d.y & 0xffffu); s += f; s2 += f * f;
        f = bf2f(d.y >> 16);     s += f; s2 += f * f;
        f = bf2f(d.z & 0xffffu); s += f; s2 += f * f;
        f = bf2f(d.z >> 16);     s += f; s2 += f * f;
        f = bf2f(d.w & 0xffffu); s += f; s2 += f * f;
        f = bf2f(d.w >> 16);     s += f; s2 += f * f;
    }
#pragma unroll
    for (int m = 1; m < 64; m <<= 1) {
        s  += __shfl_xor(s, m);
        s2 += __shfl_xor(s2, m);
    }
    __shared__ float rs[4], rs2[4];
    int wave = tid >> 6, lane = tid & 63;
    if (lane == 0) { rs[wave] = s; rs2[wave] = s2; }
    __syncthreads();
    if (tid == 0) {
        ps[blockIdx.x * 2]     = rs[0] + rs[1] + rs[2] + rs[3];
        ps[blockIdx.x * 2 + 1] = rs2[0] + rs2[1] + rs2[2] + rs2[3];
    }
}

// ---------------- kernel 4b: finalize affine coefs ----------------
__global__ __launch_bounds__(128) void k_ab(const float* __restrict__ ps,
                                            const float* __restrict__ gamma,
                                            const float* __restrict__ beta,
                                            float* __restrict__ ab) {
    int c = threadIdx.x;
    float S  = ps[(c * 4 + 0) * 2] + ps[(c * 4 + 1) * 2] + ps[(c * 4 + 2) * 2] + ps[(c * 4 + 3) * 2];
    float S2 = ps[(c * 4 + 0) * 2 + 1] + ps[(c * 4 + 1) * 2 + 1] + ps[(c * 4 + 2) * 2 + 1] + ps[(c * 4 + 3) * 2 + 1];
    float mean = S * (1.f / 262144.f);
    float var = S2 * (1.f / 262144.f) - mean * mean;
    float A = gamma[c] * rsqrtf(var + 1e-5f);
    ab[2 * c] = A;
    ab[2 * c + 1] = beta[c] - mean * A;
}

// ---------------- kernel 5: fused routing + entropy ----------------
// grid 2048; bid: k=bid&7, ch=(bid>>3)&1, unit=(bid>>4)*8+k
// unit: b = u>>7, r = (u>>5)&3, y = u&31 ; chunk covers x0 = ch*16 .. +15
__global__ __launch_bounds__(256, 4) void k_route(const unsigned short* __restrict__ pp,
                                                  const float* __restrict__ ab,
                                                  float* __restrict__ out,
                                                  float* __restrict__ ent_out) {
    int bid = blockIdx.x;
    int u = ((bid >> 4) << 3) + (bid & 7);
    int ch = (bid >> 3) & 1;
    int y = u & 31, r = (u >> 5) & 3, b = u >> 7;
    int x0 = ch * 16;
    int tid = threadIdx.x;
    int wave = tid >> 6, lane = tid & 63;
    int i_l = lane >> 3, oc_l = lane & 7;

    __shared__ unsigned int Tl2[16][8][64];      // [od][x-pair][lane(i,oc)]  32 KB
    __shared__ unsigned short vst[8][16][18];    // [oc][od][x+pad]           4.5 KB
    __shared__ float ered[4];

#pragma unroll
    for (int t4i = 0; t4i < 4; ++t4i) {
        int t4 = tid + t4i * 256;
        int od = t4 >> 6, ls = t4 & 63;
        int ii = ls >> 3, oo = ls & 7;
        int c = oo * 16 + od;
        int co4 = c * 4 + r;
        int n = b * 8 + ii;
        float A = ab[2 * c], Bv = ab[2 * c + 1];
        const uint4* src = reinterpret_cast<const uint4*>(pp + ((n * 512 + co4) * 32 + y) * 32 + x0);
        uint4 d0 = src[0], d1 = src[1];
        unsigned wds[8] = {d0.x, d0.y, d0.z, d0.w, d1.x, d1.y, d1.z, d1.w};
#pragma unroll
        for (int j = 0; j < 8; ++j) {
            float tlo = A * bf2f(wds[j] & 0xffffu) + Bv;
            float thi = A * bf2f(wds[j] >> 16) + Bv;
            Tl2[od][j][ls] = (unsigned)f2bf(tlo) | ((unsigned)f2bf(thi) << 16);
        }
    }
    __syncthreads();

    float e_acc = 0.f;

    for (int q = 0; q < 2; ++q) {
        int p2 = wave + q * 4;
        float t0[16], t1[16];
#pragma unroll
        for (int od = 0; od < 16; ++od) {
            unsigned pr = Tl2[od][p2][lane];
            t0[od] = bf2f(pr & 0xffffu);
            t1[od] = bf2f(pr >> 16);
        }

        float b0 = 0.f, b1 = 0.f, c0, c1, sc0 = 0.f, sc1 = 0.f;
        float s0[16], s1[16];
        for (int it = 0; it < 3; ++it) {
            float m0 = b0, m1 = b1;
            m0 = fmaxf(m0, dppx1(m0));      m1 = fmaxf(m1, dppx1(m1));
            m0 = fmaxf(m0, dppx2(m0));      m1 = fmaxf(m1, dppx2(m1));
            m0 = fmaxf(m0, swzf<SWZ4>(m0)); m1 = fmaxf(m1, swzf<SWZ4>(m1));
            float e0 = __expf(b0 - m0), e1 = __expf(b1 - m1);
            float se0 = e0, se1 = e1;
            se0 += dppx1(se0);      se1 += dppx1(se1);
            se0 += dppx2(se0);      se1 += dppx2(se1);
            se0 += swzf<SWZ4>(se0); se1 += swzf<SWZ4>(se1);
            c0 = e0 * __builtin_amdgcn_rcpf(se0);
            c1 = e1 * __builtin_amdgcn_rcpf(se1);
            float n20 = 0.f, n21 = 0.f;
#pragma unroll
            for (int od = 0; od < 16; ++od) {
                float v0 = c0 * t0[od], v1 = c1 * t1[od];
                v0 += swzf<SWZ8>(v0);   v1 += swzf<SWZ8>(v1);
                v0 += swzf<SWZ16>(v0);  v1 += swzf<SWZ16>(v1);
                v0 = psum32(v0);        v1 = psum32(v1);
                s0[od] = v0;            s1[od] = v1;
                n20 += v0 * v0;         n21 += v1 * v1;
            }
            float nr0 = sqrtf(n20), nr1 = sqrtf(n21);
            sc0 = n20 * __builtin_amdgcn_rcpf((1.f + n20) * (nr0 + 1e-8f));
            sc1 = n21 * __builtin_amdgcn_rcpf((1.f + n21) * (nr1 + 1e-8f));
            if (it < 2) {
                float a0 = 0.f, a1 = 0.f;
#pragma unroll
                for (int od = 0; od < 16; ++od) {
                    a0 += t0[od] * s0[od];
                    a1 += t1[od] * s1[od];
                }
                b0 += a0 * sc0;
                b1 += a1 * sc1;
            }
        }
        e_acc += -c0 * __logf(c0) - c1 * __logf(c1);
        if (i_l == 0) {
#pragma unroll
            for (int od = 0; od < 16; ++od) {
                vst[oc_l][od][2 * p2]     = f2bf(sc0 * s0[od]);
                vst[oc_l][od][2 * p2 + 1] = f2bf(sc1 * s1[od]);
            }
        }
    }

    e_acc += dppx1(e_acc);
    e_acc += dppx2(e_acc);
    e_acc += swzf<SWZ4>(e_acc);
    e_acc += swzf<SWZ8>(e_acc);
    e_acc += swzf<SWZ16>(e_acc);
    e_acc = psum32(e_acc);
    if (lane == 0) ered[wave] = e_acc;
    __syncthreads();

    {
        int xx = tid & 15, od = (tid >> 4) & 15;
#pragma unroll
        for (int oc = 0; oc < 8; ++oc) {
            out[((((b * 8 + oc) * 16 + od) * 4 + r) * 32 + y) * 32 + x0 + xx] =
                bf2f(vst[oc][od][xx]);
        }
    }
    if (tid == 0) {
        float tot = ered[0] + ered[1] + ered[2] + ered[3];
        atomicAdd(ent_out, tot * (1.0f / (2.0794415416798357f * 32768.0f)));
    }
}

extern "C" void kernel_launch(void* const* d_in, const int* in_sizes, int n_in,
                              void* d_out, int out_size, void* d_ws, size_t ws_size,
                              hipStream_t stream) {
    const float* x     = (const float*)d_in[0];  // (8,8,16,4,32,32)
    const float* w     = (const float*)d_in[1];  // (128,16,4,3,3)
    const float* gamma = (const float*)d_in[2];  // (128)
    const float* beta  = (const float*)d_in[3];  // (128)
    float* out = (float*)d_out;                  // 4,194,304 v + 1 entropy

    char* ws = (char*)d_ws;
    unsigned short* p    = (unsigned short*)ws;                                  // 67,108,864 B
    unsigned short* xpad = (unsigned short*)(ws + 67108864);                     //  9,469,952 B
    unsigned short* twb  = (unsigned short*)(ws + 67108864 + 9469952);           //    589,824 B
    float* ab            = (float*)(ws + 67108864 + 9469952 + 589824);           //      1,024 B
    float* ps            = (float*)(ws + 67108864 + 9469952 + 589824 + 1024);    //      4,096 B

    hipMemsetAsync(out + 4194304, 0, 4, stream);
    hipMemsetAsync(xpad, 0, 9469952, stream);

    k_twb<<<1152, 256, 0, stream>>>(w, twb);
    k_prep<<<2048, 256, 0, stream>>>(x, xpad);

    dim3 gconv(64, 8, 4);
    k_mconv<<<gconv, 256, 0, stream>>>(xpad, twb, p);

    k_stats1<<<512, 256, 0, stream>>>(p, ps);
    k_ab<<<1, 128, 0, stream>>>(ps, gamma, beta, ab);

    k_route<<<2048, 256, 0, stream>>>(p, ab, out, out + 4194304);
}

// Round 10
// 167.036 us; speedup vs baseline: 1.6611x; 1.0995x over previous
//
#include <hip/hip_runtime.h>
#include <hip/hip_bf16.h>

// B=8 IC=8 ID=16 OC=8 OD=16 H=W=32 K=3 ITER=3
// conv as MFMA GEMM per image: A=tw (512 co4 x 576 k), B=im2col(x) (576 k x 1024 pos)
// p stored route-friendly: p2[r][y][ch][n][c][x16] (r=co4&3, c=co4>>2, ch=x>>4), bf16, 64MB
// v output: (B, OC, OD, 4, H, W) = 4,194,304 fp32; entropy scalar at out[4194304]

typedef short bf16x8 __attribute__((ext_vector_type(8)));
typedef float f32x4 __attribute__((ext_vector_type(4)));
typedef unsigned int u32x2 __attribute__((ext_vector_type(2)));

__device__ inline float bf2f(unsigned int u) {
    union { unsigned int i; float f; } x;
    x.i = u << 16;
    return x.f;
}
__device__ inline unsigned short f2bf(float f) {
    union { float f; unsigned int u; } x;
    x.f = f;
    unsigned int r = x.u + 0x7fffu + ((x.u >> 16) & 1u);
    return (unsigned short)(r >> 16);
}

// cross-lane helpers (all-lanes-active contexts only)
__device__ inline float dppx1(float x) {
    return __int_as_float(__builtin_amdgcn_update_dpp(0, __float_as_int(x), 0xB1, 0xF, 0xF, false));
}
__device__ inline float dppx2(float x) {
    return __int_as_float(__builtin_amdgcn_update_dpp(0, __float_as_int(x), 0x4E, 0xF, 0xF, false));
}
template <int PATT>
__device__ inline float swzf(float x) {
    return __int_as_float(__builtin_amdgcn_ds_swizzle(__float_as_int(x), PATT));
}
#define SWZ4  0x101F
#define SWZ8  0x201F
#define SWZ16 0x401F
__device__ inline float psum32(float x) {  // x + x[lane^32]
    u32x2 r = __builtin_amdgcn_permlane32_swap(__float_as_uint(x), __float_as_uint(x), false, false);
    return __uint_as_float(r[0]) + __uint_as_float(r[1]);
}

// ---------------- kernel 1: transformed weights, bf16, pre-swizzled ----------------
// twb[tap][co4][ci'] : [9][512][64] bf16 ; stored ci' = ci ^ ((co4&7)<<3)
__global__ __launch_bounds__(256) void k_twb(const float* __restrict__ w,
                                             unsigned short* __restrict__ twb) {
    int idx = blockIdx.x * 256 + threadIdx.x;
    int tap = idx >> 15;
    int rem = idx & 32767;
    int co4 = rem >> 6;
    int cst = rem & 63;
    int ci = cst ^ ((co4 & 7) << 3);
    int r = co4 & 3, co = co4 >> 2;
    int s = ci & 3, cicap = ci >> 2;
    int ky = tap / 3, kx = tap % 3;
    int sy, sx;
    switch (r) {
        case 0: sy = ky;      sx = kx;      break;
        case 1: sy = kx;      sx = 2 - ky;  break;
        case 2: sy = 2 - ky;  sx = 2 - kx;  break;
        default: sy = 2 - kx; sx = ky;      break;
    }
    int ss = (s - r) & 3;
    twb[idx] = f2bf(w[(((co * 16 + cicap) * 4 + ss) * 3 + sy) * 3 + sx]);
}

// ---------------- kernel 2: pad + transpose + bf16 + swizzle the input ----------------
// xpad[n][yy][xx][ci'] : [64][34][34][64] bf16 ; ci' = ci ^ ((xx&7)<<3); borders pre-zeroed
__global__ __launch_bounds__(256) void k_prep(const float* __restrict__ xf,
                                              unsigned short* __restrict__ xpad) {
    int n = blockIdx.x >> 5, y = blockIdx.x & 31;
    int tid = threadIdx.x;
    __shared__ float tile[64][33];
#pragma unroll
    for (int it = 0; it < 8; ++it) {
        int ci = it * 8 + (tid >> 5), x = tid & 31;
        tile[ci][x] = xf[((n * 64 + ci) * 32 + y) * 32 + x];
    }
    __syncthreads();
    int xx = 1 + (tid >> 3), g = tid & 7;
    int x = xx - 1;
    int lg = g ^ (xx & 7);
    unsigned short vals[8];
#pragma unroll
    for (int j = 0; j < 8; ++j) vals[j] = f2bf(tile[lg * 8 + j][x]);
    uint4 pk;
    pk.x = (unsigned)vals[0] | ((unsigned)vals[1] << 16);
    pk.y = (unsigned)vals[2] | ((unsigned)vals[3] << 16);
    pk.z = (unsigned)vals[4] | ((unsigned)vals[5] << 16);
    pk.w = (unsigned)vals[6] | ((unsigned)vals[7] << 16);
    *reinterpret_cast<uint4*>(&xpad[(n * 34 + (y + 1)) * 2176 + xx * 64 + g * 8]) = pk;
}

// ---------------- kernel 3: MFMA conv (round-5 proven structure; p2 epilogue) ----------------
// grid (64 n, 8 yt, 4 cot), 256 threads = 4 waves in 2x2
// wave tile: 64 co4 x 64 pos (4x4 frags 16x16), K = 9 taps x 2 steps of 32
__global__ __launch_bounds__(256, 3) void k_mconv(const unsigned short* __restrict__ xpad,
                                                  const unsigned short* __restrict__ twb,
                                                  unsigned short* __restrict__ p2) {
    int n = blockIdx.x, yt = blockIdx.y, cot = blockIdx.z;
    int y0 = yt * 4;
    int tid = threadIdx.x, lane = tid & 63, wave = tid >> 6;
    int wm = (wave >> 1) * 64, wn = (wave & 1) * 64;
    int p15 = lane & 15, hi = lane >> 4;

    __shared__ unsigned short xs[6 * 34 * 64];   // 26112 B
    __shared__ unsigned short wA[128 * 64];      // 16384 B

    {
        const uint4* src = reinterpret_cast<const uint4*>(xpad + (n * 34 + y0) * 2176);
        uint4* dst = reinterpret_cast<uint4*>(xs);
        for (int t = tid; t < 1632; t += 256) dst[t] = src[t];
    }

    f32x4 acc[4][4];
#pragma unroll
    for (int mf = 0; mf < 4; ++mf)
#pragma unroll
        for (int nf = 0; nf < 4; ++nf) acc[mf][nf] = (f32x4){0.f, 0.f, 0.f, 0.f};

    int yl[4], xb[4];
#pragma unroll
    for (int nf = 0; nf < 4; ++nf) {
        int posl = wn + nf * 16 + p15;
        yl[nf] = posl >> 5;
        xb[nf] = posl & 31;
    }

    for (int tap = 0; tap < 9; ++tap) {
        __syncthreads();
        {
            const uint4* wsrc = reinterpret_cast<const uint4*>(twb + (tap * 512 + cot * 128) * 64);
            uint4* wdst = reinterpret_cast<uint4*>(wA);
            for (int t = tid; t < 1024; t += 256) wdst[t] = wsrc[t];
        }
        __syncthreads();

        int ky = tap / 3, kx = tap % 3;

        bf16x8 a[4][2], b[4][2];
#pragma unroll
        for (int mf = 0; mf < 4; ++mf) {
            int co4l = wm + mf * 16 + p15;
#pragma unroll
            for (int s = 0; s < 2; ++s) {
                int cig = hi + s * 4;
                a[mf][s] = *reinterpret_cast<const bf16x8*>(
                    &wA[co4l * 64 + ((cig ^ (co4l & 7)) << 3)]);
            }
        }
#pragma unroll
        for (int nf = 0; nf < 4; ++nf) {
            int row = yl[nf] + ky, col = xb[nf] + kx;
#pragma unroll
            for (int s = 0; s < 2; ++s) {
                int cig = hi + s * 4;
                b[nf][s] = *reinterpret_cast<const bf16x8*>(
                    &xs[(row * 34 + col) * 64 + ((cig ^ (col & 7)) << 3)]);
            }
        }
#pragma unroll
        for (int s = 0; s < 2; ++s)
#pragma unroll
            for (int mf = 0; mf < 4; ++mf)
#pragma unroll
                for (int nf = 0; nf < 4; ++nf)
                    acc[mf][nf] = __builtin_amdgcn_mfma_f32_16x16x32_bf16(
                        a[mf][s], b[nf][s], acc[mf][nf], 0, 0, 0);
    }

    // epilogue -> p2[r][y][ch][n][c][x16]; r=reg, c=cot*32+(wm>>2)+mf*4+hi, x16=p15
    // one store per (mf,nf,reg) covers c..c+3 x 16x = 128B wave-contiguous
#pragma unroll
    for (int mf = 0; mf < 4; ++mf) {
        int c = cot * 32 + (wm >> 2) + mf * 4 + hi;
#pragma unroll
        for (int nf = 0; nf < 4; ++nf) {
            int posl = wn + nf * 16 + p15;
            int y = y0 + (posl >> 5);
            int ch = (posl >> 4) & 1;
#pragma unroll
            for (int reg = 0; reg < 4; ++reg) {
                int idx = ((((reg * 32 + y) * 2 + ch) * 64 + n) * 128 + c) * 16 + p15;
                p2[idx] = f2bf(acc[mf][nf][reg]);
            }
        }
    }
}

// ---------------- kernel 4a: BN partial sums over p2, fully coalesced ----------------
// 512 blocks; each scans a contiguous 128KB region (32 slabs x 2048 elems).
// Within a slab, thread t's uint4 covers channel c = t>>1 (constant across slabs).
__global__ __launch_bounds__(256) void k_stats1(const unsigned short* __restrict__ pp,
                                                float* __restrict__ ps) {
    int blk = blockIdx.x, tid = threadIdx.x;
    const uint4* base = reinterpret_cast<const uint4*>(pp) + blk * 8192;
    float s = 0.f, s2 = 0.f;
#pragma unroll 4
    for (int k = 0; k < 32; ++k) {
        uint4 d = base[k * 256 + tid];
        float f;
        f = bf2f(d.x & 0xffffu); s += f; s2 += f * f;
        f = bf2f(d.x >> 16);     s += f; s2 += f * f;
        f = bf2f(d.y & 0xffffu); s += f; s2 += f * f;
        f = bf2f(d.y >> 16);     s += f; s2 += f * f;
        f = bf2f(d.z & 0xffffu); s += f; s2 += f * f;
        f = bf2f(d.z >> 16);     s += f; s2 += f * f;
        f = bf2f(d.w & 0xffffu); s += f; s2 += f * f;
        f = bf2f(d.w >> 16);     s += f; s2 += f * f;
    }
    s  += __shfl_xor(s, 1);
    s2 += __shfl_xor(s2, 1);
    if ((tid & 1) == 0) {
        int c = tid >> 1;
        ps[(blk * 128 + c) * 2]     = s;
        ps[(blk * 128 + c) * 2 + 1] = s2;
    }
}

// ---------------- kernel 4b: finalize affine coefs ----------------
__global__ __launch_bounds__(256) void k_ab(const float* __restrict__ ps,
                                            const float* __restrict__ gamma,
                                            const float* __restrict__ beta,
                                            float* __restrict__ ab) {
    int c = threadIdx.x >> 1, h = threadIdx.x & 1;
    float S = 0.f, S2 = 0.f;
    for (int b = h * 256; b < h * 256 + 256; ++b) {
        S  += ps[(b * 128 + c) * 2];
        S2 += ps[(b * 128 + c) * 2 + 1];
    }
    S  += __shfl_xor(S, 1);
    S2 += __shfl_xor(S2, 1);
    if (h == 0) {
        float mean = S * (1.f / 262144.f);
        float var = S2 * (1.f / 262144.f) - mean * mean;
        float A = gamma[c] * rsqrtf(var + 1e-5f);
        ab[2 * c] = A;
        ab[2 * c + 1] = beta[c] - mean * A;
    }
}

// ---------------- kernel 5: fused routing + entropy (p2 input, contiguous stage) ----------------
// grid 2048; bid: k=bid&7, ch=(bid>>3)&1, unit=(bid>>4)*8+k
// unit: b = u>>7, r = (u>>5)&3, y = u&31. Block region = 32KB contiguous in p2.
__global__ __launch_bounds__(256, 4) void k_route(const unsigned short* __restrict__ pp,
                                                  const float* __restrict__ ab,
                                                  float* __restrict__ out,
                                                  float* __restrict__ ent_out) {
    int bid = blockIdx.x;
    int u = ((bid >> 4) << 3) + (bid & 7);
    int ch = (bid >> 3) & 1;
    int y = u & 31, r = (u >> 5) & 3, b = u >> 7;
    int x0 = ch * 16;
    int tid = threadIdx.x;
    int wave = tid >> 6, lane = tid & 63;
    int i_l = lane >> 3, oc_l = lane & 7;

    __shared__ unsigned int Tl2[16][8][64];      // [od][x-pair][lane(i,oc)]  32 KB
    __shared__ unsigned short vst[8][16][18];    // [oc][od][x+pad]           4.5 KB
    __shared__ float ered[4];

    // ---- stage: one contiguous 32KB slab; slot = i*256 + c*2 + half ----
    const uint4* src = reinterpret_cast<const uint4*>(pp) +
                       (((((r * 32 + y) * 2 + ch) * 64) + b * 8) << 8);
#pragma unroll
    for (int pass = 0; pass < 8; ++pass) {
        int slot = pass * 256 + tid;
        int il = slot >> 8, c = (slot >> 1) & 127, half = slot & 1;
        int od = c & 15, oo = c >> 4;
        int ls = il * 8 + oo;
        float A = ab[2 * c], Bv = ab[2 * c + 1];
        uint4 d = src[slot];
        unsigned wds[4] = {d.x, d.y, d.z, d.w};
#pragma unroll
        for (int jj = 0; jj < 4; ++jj) {
            float tlo = A * bf2f(wds[jj] & 0xffffu) + Bv;
            float thi = A * bf2f(wds[jj] >> 16) + Bv;
            Tl2[od][half * 4 + jj][ls] = (unsigned)f2bf(tlo) | ((unsigned)f2bf(thi) << 16);
        }
    }
    __syncthreads();

    float e_acc = 0.f;

    for (int q = 0; q < 2; ++q) {
        int p2i = wave + q * 4;
        float t0[16], t1[16];
#pragma unroll
        for (int od = 0; od < 16; ++od) {
            unsigned pr = Tl2[od][p2i][lane];
            t0[od] = bf2f(pr & 0xffffu);
            t1[od] = bf2f(pr >> 16);
        }

        float b0 = 0.f, b1 = 0.f, c0, c1, sc0 = 0.f, sc1 = 0.f;
        float s0[16], s1[16];
        for (int it = 0; it < 3; ++it) {
            float m0 = b0, m1 = b1;
            m0 = fmaxf(m0, dppx1(m0));      m1 = fmaxf(m1, dppx1(m1));
            m0 = fmaxf(m0, dppx2(m0));      m1 = fmaxf(m1, dppx2(m1));
            m0 = fmaxf(m0, swzf<SWZ4>(m0)); m1 = fmaxf(m1, swzf<SWZ4>(m1));
            float e0 = __expf(b0 - m0), e1 = __expf(b1 - m1);
            float se0 = e0, se1 = e1;
            se0 += dppx1(se0);      se1 += dppx1(se1);
            se0 += dppx2(se0);      se1 += dppx2(se1);
            se0 += swzf<SWZ4>(se0); se1 += swzf<SWZ4>(se1);
            c0 = e0 * __builtin_amdgcn_rcpf(se0);
            c1 = e1 * __builtin_amdgcn_rcpf(se1);
            float n20 = 0.f, n21 = 0.f;
#pragma unroll
            for (int od = 0; od < 16; ++od) {
                float v0 = c0 * t0[od], v1 = c1 * t1[od];
                v0 += swzf<SWZ8>(v0);   v1 += swzf<SWZ8>(v1);
                v0 += swzf<SWZ16>(v0);  v1 += swzf<SWZ16>(v1);
                v0 = psum32(v0);        v1 = psum32(v1);
                s0[od] = v0;            s1[od] = v1;
                n20 += v0 * v0;         n21 += v1 * v1;
            }
            float nr0 = sqrtf(n20), nr1 = sqrtf(n21);
            sc0 = n20 * __builtin_amdgcn_rcpf((1.f + n20) * (nr0 + 1e-8f));
            sc1 = n21 * __builtin_amdgcn_rcpf((1.f + n21) * (nr1 + 1e-8f));
            if (it < 2) {
                float a0 = 0.f, a1 = 0.f;
#pragma unroll
                for (int od = 0; od < 16; ++od) {
                    a0 += t0[od] * s0[od];
                    a1 += t1[od] * s1[od];
                }
                b0 += a0 * sc0;
                b1 += a1 * sc1;
            }
        }
        e_acc += -c0 * __logf(c0) - c1 * __logf(c1);
        if (i_l == 0) {
#pragma unroll
            for (int od = 0; od < 16; ++od) {
                vst[oc_l][od][2 * p2i]     = f2bf(sc0 * s0[od]);
                vst[oc_l][od][2 * p2i + 1] = f2bf(sc1 * s1[od]);
            }
        }
    }

    e_acc += dppx1(e_acc);
    e_acc += dppx2(e_acc);
    e_acc += swzf<SWZ4>(e_acc);
    e_acc += swzf<SWZ8>(e_acc);
    e_acc += swzf<SWZ16>(e_acc);
    e_acc = psum32(e_acc);
    if (lane == 0) ered[wave] = e_acc;
    __syncthreads();

    {
        int xx = tid & 15, od = (tid >> 4) & 15;
#pragma unroll
        for (int oc = 0; oc < 8; ++oc) {
            out[((((b * 8 + oc) * 16 + od) * 4 + r) * 32 + y) * 32 + x0 + xx] =
                bf2f(vst[oc][od][xx]);
        }
    }
    if (tid == 0) {
        float tot = ered[0] + ered[1] + ered[2] + ered[3];
        atomicAdd(ent_out, tot * (1.0f / (2.0794415416798357f * 32768.0f)));
    }
}

extern "C" void kernel_launch(void* const* d_in, const int* in_sizes, int n_in,
                              void* d_out, int out_size, void* d_ws, size_t ws_size,
                              hipStream_t stream) {
    const float* x     = (const float*)d_in[0];  // (8,8,16,4,32,32)
    const float* w     = (const float*)d_in[1];  // (128,16,4,3,3)
    const float* gamma = (const float*)d_in[2];  // (128)
    const float* beta  = (const float*)d_in[3];  // (128)
    float* out = (float*)d_out;                  // 4,194,304 v + 1 entropy

    char* ws = (char*)d_ws;
    unsigned short* p2   = (unsigned short*)ws;                                  // 67,108,864 B
    unsigned short* xpad = (unsigned short*)(ws + 67108864);                     //  9,469,952 B
    unsigned short* twb  = (unsigned short*)(ws + 67108864 + 9469952);           //    589,824 B
    float* ab            = (float*)(ws + 67108864 + 9469952 + 589824);           //      1,024 B
    float* ps            = (float*)(ws + 67108864 + 9469952 + 589824 + 1024);    //    524,288 B

    hipMemsetAsync(out + 4194304, 0, 4, stream);
    hipMemsetAsync(xpad, 0, 9469952, stream);

    k_twb<<<1152, 256, 0, stream>>>(w, twb);
    k_prep<<<2048, 256, 0, stream>>>(x, xpad);

    dim3 gconv(64, 8, 4);
    k_mconv<<<gconv, 256, 0, stream>>>(xpad, twb, p2);

    k_stats1<<<512, 256, 0, stream>>>(p2, ps);
    k_ab<<<1, 256, 0, stream>>>(ps, gamma, beta, ab);

    k_route<<<2048, 256, 0, stream>>>(p2, ab, out, out + 4194304);
}

// Round 11
// 148.302 us; speedup vs baseline: 1.8709x; 1.1263x over previous
//
#include <hip/hip_runtime.h>
#include <hip/hip_bf16.h>

// B=8 IC=8 ID=16 OC=8 OD=16 H=W=32 K=3 ITER=3
// conv as MFMA GEMM per image: A=tw (512 co4 x 576 k), B=im2col(x) (576 k x 1024 pos)
// p stored route-friendly: p2[r][y][ch][n][c][x16] (r=co4&3, c=co4>>2, ch=x>>4), bf16, 64MB
// v output: (B, OC, OD, 4, H, W) = 4,194,304 fp32; entropy scalar at out[4194304]

typedef short bf16x8 __attribute__((ext_vector_type(8)));
typedef float f32x4 __attribute__((ext_vector_type(4)));
typedef unsigned int u32x2 __attribute__((ext_vector_type(2)));

__device__ inline float bf2f(unsigned int u) {
    union { unsigned int i; float f; } x;
    x.i = u << 16;
    return x.f;
}
__device__ inline unsigned short f2bf(float f) {
    union { float f; unsigned int u; } x;
    x.f = f;
    unsigned int r = x.u + 0x7fffu + ((x.u >> 16) & 1u);
    return (unsigned short)(r >> 16);
}

// cross-lane helpers (all-lanes-active contexts only)
__device__ inline float dppx1(float x) {
    return __int_as_float(__builtin_amdgcn_update_dpp(0, __float_as_int(x), 0xB1, 0xF, 0xF, false));
}
__device__ inline float dppx2(float x) {
    return __int_as_float(__builtin_amdgcn_update_dpp(0, __float_as_int(x), 0x4E, 0xF, 0xF, false));
}
template <int PATT>
__device__ inline float swzf(float x) {
    return __int_as_float(__builtin_amdgcn_ds_swizzle(__float_as_int(x), PATT));
}
#define SWZ4  0x101F
#define SWZ8  0x201F
#define SWZ16 0x401F
__device__ inline float psum32(float x) {  // x + x[lane^32]
    u32x2 r = __builtin_amdgcn_permlane32_swap(__float_as_uint(x), __float_as_uint(x), false, false);
    return __uint_as_float(r[0]) + __uint_as_float(r[1]);
}

// ---------------- kernel 1: transformed weights, bf16, pre-swizzled ----------------
// twb[tap][co4][ci'] : [9][512][64] bf16 ; stored ci' = ci ^ ((co4&7)<<3)
__global__ __launch_bounds__(256) void k_twb(const float* __restrict__ w,
                                             unsigned short* __restrict__ twb) {
    int idx = blockIdx.x * 256 + threadIdx.x;
    int tap = idx >> 15;
    int rem = idx & 32767;
    int co4 = rem >> 6;
    int cst = rem & 63;
    int ci = cst ^ ((co4 & 7) << 3);
    int r = co4 & 3, co = co4 >> 2;
    int s = ci & 3, cicap = ci >> 2;
    int ky = tap / 3, kx = tap % 3;
    int sy, sx;
    switch (r) {
        case 0: sy = ky;      sx = kx;      break;
        case 1: sy = kx;      sx = 2 - ky;  break;
        case 2: sy = 2 - ky;  sx = 2 - kx;  break;
        default: sy = 2 - kx; sx = ky;      break;
    }
    int ss = (s - r) & 3;
    twb[idx] = f2bf(w[(((co * 16 + cicap) * 4 + ss) * 3 + sy) * 3 + sx]);
}

// ---------------- kernel 2: pad + transpose + bf16 + swizzle the input ----------------
// xpad[n][yy][xx][ci'] : [64][34][34][64] bf16 ; ci' = ci ^ ((xx&7)<<3); borders pre-zeroed
__global__ __launch_bounds__(256) void k_prep(const float* __restrict__ xf,
                                              unsigned short* __restrict__ xpad) {
    int n = blockIdx.x >> 5, y = blockIdx.x & 31;
    int tid = threadIdx.x;
    __shared__ float tile[64][33];
#pragma unroll
    for (int it = 0; it < 8; ++it) {
        int ci = it * 8 + (tid >> 5), x = tid & 31;
        tile[ci][x] = xf[((n * 64 + ci) * 32 + y) * 32 + x];
    }
    __syncthreads();
    int xx = 1 + (tid >> 3), g = tid & 7;
    int x = xx - 1;
    int lg = g ^ (xx & 7);
    unsigned short vals[8];
#pragma unroll
    for (int j = 0; j < 8; ++j) vals[j] = f2bf(tile[lg * 8 + j][x]);
    uint4 pk;
    pk.x = (unsigned)vals[0] | ((unsigned)vals[1] << 16);
    pk.y = (unsigned)vals[2] | ((unsigned)vals[3] << 16);
    pk.z = (unsigned)vals[4] | ((unsigned)vals[5] << 16);
    pk.w = (unsigned)vals[6] | ((unsigned)vals[7] << 16);
    *reinterpret_cast<uint4*>(&xpad[(n * 34 + (y + 1)) * 2176 + xx * 64 + g * 8]) = pk;
}

// ---------------- kernel 3: MFMA conv (round-5 proven structure; p2 epilogue) ----------------
// grid (64 n, 8 yt, 4 cot), 256 threads = 4 waves in 2x2
// wave tile: 64 co4 x 64 pos (4x4 frags 16x16), K = 9 taps x 2 steps of 32
__global__ __launch_bounds__(256, 3) void k_mconv(const unsigned short* __restrict__ xpad,
                                                  const unsigned short* __restrict__ twb,
                                                  unsigned short* __restrict__ p2) {
    int n = blockIdx.x, yt = blockIdx.y, cot = blockIdx.z;
    int y0 = yt * 4;
    int tid = threadIdx.x, lane = tid & 63, wave = tid >> 6;
    int wm = (wave >> 1) * 64, wn = (wave & 1) * 64;
    int p15 = lane & 15, hi = lane >> 4;

    __shared__ unsigned short xs[6 * 34 * 64];   // 26112 B
    __shared__ unsigned short wA[128 * 64];      // 16384 B

    {
        const uint4* src = reinterpret_cast<const uint4*>(xpad + (n * 34 + y0) * 2176);
        uint4* dst = reinterpret_cast<uint4*>(xs);
        for (int t = tid; t < 1632; t += 256) dst[t] = src[t];
    }

    f32x4 acc[4][4];
#pragma unroll
    for (int mf = 0; mf < 4; ++mf)
#pragma unroll
        for (int nf = 0; nf < 4; ++nf) acc[mf][nf] = (f32x4){0.f, 0.f, 0.f, 0.f};

    int yl[4], xb[4];
#pragma unroll
    for (int nf = 0; nf < 4; ++nf) {
        int posl = wn + nf * 16 + p15;
        yl[nf] = posl >> 5;
        xb[nf] = posl & 31;
    }

    for (int tap = 0; tap < 9; ++tap) {
        __syncthreads();
        {
            const uint4* wsrc = reinterpret_cast<const uint4*>(twb + (tap * 512 + cot * 128) * 64);
            uint4* wdst = reinterpret_cast<uint4*>(wA);
            for (int t = tid; t < 1024; t += 256) wdst[t] = wsrc[t];
        }
        __syncthreads();

        int ky = tap / 3, kx = tap % 3;

        bf16x8 a[4][2], b[4][2];
#pragma unroll
        for (int mf = 0; mf < 4; ++mf) {
            int co4l = wm + mf * 16 + p15;
#pragma unroll
            for (int s = 0; s < 2; ++s) {
                int cig = hi + s * 4;
                a[mf][s] = *reinterpret_cast<const bf16x8*>(
                    &wA[co4l * 64 + ((cig ^ (co4l & 7)) << 3)]);
            }
        }
#pragma unroll
        for (int nf = 0; nf < 4; ++nf) {
            int row = yl[nf] + ky, col = xb[nf] + kx;
#pragma unroll
            for (int s = 0; s < 2; ++s) {
                int cig = hi + s * 4;
                b[nf][s] = *reinterpret_cast<const bf16x8*>(
                    &xs[(row * 34 + col) * 64 + ((cig ^ (col & 7)) << 3)]);
            }
        }
#pragma unroll
        for (int s = 0; s < 2; ++s)
#pragma unroll
            for (int mf = 0; mf < 4; ++mf)
#pragma unroll
                for (int nf = 0; nf < 4; ++nf)
                    acc[mf][nf] = __builtin_amdgcn_mfma_f32_16x16x32_bf16(
                        a[mf][s], b[nf][s], acc[mf][nf], 0, 0, 0);
    }

    // epilogue -> p2[r][y][ch][n][c][x16]; r=reg, c=cot*32+(wm>>2)+mf*4+hi, x16=p15
#pragma unroll
    for (int mf = 0; mf < 4; ++mf) {
        int c = cot * 32 + (wm >> 2) + mf * 4 + hi;
#pragma unroll
        for (int nf = 0; nf < 4; ++nf) {
            int posl = wn + nf * 16 + p15;
            int y = y0 + (posl >> 5);
            int ch = (posl >> 4) & 1;
#pragma unroll
            for (int reg = 0; reg < 4; ++reg) {
                int idx = ((((reg * 32 + y) * 2 + ch) * 64 + n) * 128 + c) * 16 + p15;
                p2[idx] = f2bf(acc[mf][nf][reg]);
            }
        }
    }
}

// ---------------- kernel 4a: BN partial sums over p2, fully coalesced ----------------
__global__ __launch_bounds__(256) void k_stats1(const unsigned short* __restrict__ pp,
                                                float* __restrict__ ps) {
    int blk = blockIdx.x, tid = threadIdx.x;
    const uint4* base = reinterpret_cast<const uint4*>(pp) + blk * 8192;
    float s = 0.f, s2 = 0.f;
#pragma unroll 4
    for (int k = 0; k < 32; ++k) {
        uint4 d = base[k * 256 + tid];
        float f;
        f = bf2f(d.x & 0xffffu); s += f; s2 += f * f;
        f = bf2f(d.x >> 16);     s += f; s2 += f * f;
        f = bf2f(d.y & 0xffffu); s += f; s2 += f * f;
        f = bf2f(d.y >> 16);     s += f; s2 += f * f;
        f = bf2f(d.z & 0xffffu); s += f; s2 += f * f;
        f = bf2f(d.z >> 16);     s += f; s2 += f * f;
        f = bf2f(d.w & 0xffffu); s += f; s2 += f * f;
        f = bf2f(d.w >> 16);     s += f; s2 += f * f;
    }
    s  += __shfl_xor(s, 1);
    s2 += __shfl_xor(s2, 1);
    if ((tid & 1) == 0) {
        int c = tid >> 1;
        ps[(blk * 128 + c) * 2]     = s;
        ps[(blk * 128 + c) * 2 + 1] = s2;
    }
}

// ---------------- kernel 4b: finalize affine coefs ----------------
__global__ __launch_bounds__(256) void k_ab(const float* __restrict__ ps,
                                            const float* __restrict__ gamma,
                                            const float* __restrict__ beta,
                                            float* __restrict__ ab) {
    int c = threadIdx.x >> 1, h = threadIdx.x & 1;
    float S = 0.f, S2 = 0.f;
    for (int b = h * 256; b < h * 256 + 256; ++b) {
        S  += ps[(b * 128 + c) * 2];
        S2 += ps[(b * 128 + c) * 2 + 1];
    }
    S  += __shfl_xor(S, 1);
    S2 += __shfl_xor(S2, 1);
    if (h == 0) {
        float mean = S * (1.f / 262144.f);
        float var = S2 * (1.f / 262144.f) - mean * mean;
        float A = gamma[c] * rsqrtf(var + 1e-5f);
        ab[2 * c] = A;
        ab[2 * c + 1] = beta[c] - mean * A;
    }
}

// ---------------- kernel 5: fused routing + entropy (p2 input, contiguous stage) ----------------
// grid 2048; bid: k=bid&7, ch=(bid>>3)&1, unit=(bid>>4)*8+k
// unit: b = u>>7, r = (u>>5)&3, y = u&31. Block region = 32KB contiguous in p2.
// Tl2 lane index bank-swizzled by od<<1: write ls^(od<<1), read lane^(od<<1) -> 2-way max.
__global__ __launch_bounds__(256, 4) void k_route(const unsigned short* __restrict__ pp,
                                                  const float* __restrict__ ab,
                                                  float* __restrict__ out,
                                                  float* __restrict__ ent_out) {
    int bid = blockIdx.x;
    int u = ((bid >> 4) << 3) + (bid & 7);
    int ch = (bid >> 3) & 1;
    int y = u & 31, r = (u >> 5) & 3, b = u >> 7;
    int x0 = ch * 16;
    int tid = threadIdx.x;
    int wave = tid >> 6, lane = tid & 63;
    int i_l = lane >> 3, oc_l = lane & 7;

    __shared__ unsigned int Tl2[16][8][64];      // [od][x-pair][lane'(swz)]  32 KB
    __shared__ unsigned short vst[8][16][18];    // [oc][od][x+pad]           4.5 KB
    __shared__ float ered[4];

    // ---- stage: one contiguous 32KB slab; slot = i*256 + c*2 + half ----
    const uint4* src = reinterpret_cast<const uint4*>(pp) +
                       (((((r * 32 + y) * 2 + ch) * 64) + b * 8) << 8);
#pragma unroll
    for (int pass = 0; pass < 8; ++pass) {
        int slot = pass * 256 + tid;
        int il = slot >> 8, c = (slot >> 1) & 127, half = slot & 1;
        int od = c & 15, oo = c >> 4;
        int ls = (il * 8 + oo) ^ (od << 1);      // bank-swizzled lane slot
        float A = ab[2 * c], Bv = ab[2 * c + 1];
        uint4 d = src[slot];
        unsigned wds[4] = {d.x, d.y, d.z, d.w};
#pragma unroll
        for (int jj = 0; jj < 4; ++jj) {
            float tlo = A * bf2f(wds[jj] & 0xffffu) + Bv;
            float thi = A * bf2f(wds[jj] >> 16) + Bv;
            Tl2[od][half * 4 + jj][ls] = (unsigned)f2bf(tlo) | ((unsigned)f2bf(thi) << 16);
        }
    }
    __syncthreads();

    float e_acc = 0.f;

    for (int q = 0; q < 2; ++q) {
        int p2i = wave + q * 4;
        float t0[16], t1[16];
#pragma unroll
        for (int od = 0; od < 16; ++od) {
            unsigned pr = Tl2[od][p2i][lane ^ (od << 1)];
            t0[od] = bf2f(pr & 0xffffu);
            t1[od] = bf2f(pr >> 16);
        }

        float b0 = 0.f, b1 = 0.f, c0, c1, sc0 = 0.f, sc1 = 0.f;
        float s0[16], s1[16];
        for (int it = 0; it < 3; ++it) {
            float m0 = b0, m1 = b1;
            m0 = fmaxf(m0, dppx1(m0));      m1 = fmaxf(m1, dppx1(m1));
            m0 = fmaxf(m0, dppx2(m0));      m1 = fmaxf(m1, dppx2(m1));
            m0 = fmaxf(m0, swzf<SWZ4>(m0)); m1 = fmaxf(m1, swzf<SWZ4>(m1));
            float e0 = __expf(b0 - m0), e1 = __expf(b1 - m1);
            float se0 = e0, se1 = e1;
            se0 += dppx1(se0);      se1 += dppx1(se1);
            se0 += dppx2(se0);      se1 += dppx2(se1);
            se0 += swzf<SWZ4>(se0); se1 += swzf<SWZ4>(se1);
            c0 = e0 * __builtin_amdgcn_rcpf(se0);
            c1 = e1 * __builtin_amdgcn_rcpf(se1);
            float n20 = 0.f, n21 = 0.f;
#pragma unroll
            for (int od = 0; od < 16; ++od) {
                float v0 = c0 * t0[od], v1 = c1 * t1[od];
                v0 += swzf<SWZ8>(v0);   v1 += swzf<SWZ8>(v1);
                v0 += swzf<SWZ16>(v0);  v1 += swzf<SWZ16>(v1);
                v0 = psum32(v0);        v1 = psum32(v1);
                s0[od] = v0;            s1[od] = v1;
                n20 += v0 * v0;         n21 += v1 * v1;
            }
            float nr0 = sqrtf(n20), nr1 = sqrtf(n21);
            sc0 = n20 * __builtin_amdgcn_rcpf((1.f + n20) * (nr0 + 1e-8f));
            sc1 = n21 * __builtin_amdgcn_rcpf((1.f + n21) * (nr1 + 1e-8f));
            if (it < 2) {
                float a0 = 0.f, a1 = 0.f;
#pragma unroll
                for (int od = 0; od < 16; ++od) {
                    a0 += t0[od] * s0[od];
                    a1 += t1[od] * s1[od];
                }
                b0 += a0 * sc0;
                b1 += a1 * sc1;
            }
        }
        e_acc += -c0 * __logf(c0) - c1 * __logf(c1);
        if (i_l == 0) {
#pragma unroll
            for (int od = 0; od < 16; ++od) {
                vst[oc_l][od][2 * p2i]     = f2bf(sc0 * s0[od]);
                vst[oc_l][od][2 * p2i + 1] = f2bf(sc1 * s1[od]);
            }
        }
    }

    e_acc += dppx1(e_acc);
    e_acc += dppx2(e_acc);
    e_acc += swzf<SWZ4>(e_acc);
    e_acc += swzf<SWZ8>(e_acc);
    e_acc += swzf<SWZ16>(e_acc);
    e_acc = psum32(e_acc);
    if (lane == 0) ered[wave] = e_acc;
    __syncthreads();

    {
        int xx = tid & 15, od = (tid >> 4) & 15;
#pragma unroll
        for (int oc = 0; oc < 8; ++oc) {
            out[((((b * 8 + oc) * 16 + od) * 4 + r) * 32 + y) * 32 + x0 + xx] =
                bf2f(vst[oc][od][xx]);
        }
    }
    if (tid == 0) {
        float tot = ered[0] + ered[1] + ered[2] + ered[3];
        atomicAdd(ent_out, tot * (1.0f / (2.0794415416798357f * 32768.0f)));
    }
}

extern "C" void kernel_launch(void* const* d_in, const int* in_sizes, int n_in,
                              void* d_out, int out_size, void* d_ws, size_t ws_size,
                              hipStream_t stream) {
    const float* x     = (const float*)d_in[0];  // (8,8,16,4,32,32)
    const float* w     = (const float*)d_in[1];  // (128,16,4,3,3)
    const float* gamma = (const float*)d_in[2];  // (128)
    const float* beta  = (const float*)d_in[3];  // (128)
    float* out = (float*)d_out;                  // 4,194,304 v + 1 entropy

    char* ws = (char*)d_ws;
    unsigned short* p2   = (unsigned short*)ws;                                  // 67,108,864 B
    unsigned short* xpad = (unsigned short*)(ws + 67108864);                     //  9,469,952 B
    unsigned short* twb  = (unsigned short*)(ws + 67108864 + 9469952);           //    589,824 B
    float* ab            = (float*)(ws + 67108864 + 9469952 + 589824);           //      1,024 B
    float* ps            = (float*)(ws + 67108864 + 9469952 + 589824 + 1024);    //    524,288 B

    hipMemsetAsync(out + 4194304, 0, 4, stream);
    hipMemsetAsync(xpad, 0, 9469952, stream);

    k_twb<<<1152, 256, 0, stream>>>(w, twb);
    k_prep<<<2048, 256, 0, stream>>>(x, xpad);

    dim3 gconv(64, 8, 4);
    k_mconv<<<gconv, 256, 0, stream>>>(xpad, twb, p2);

    k_stats1<<<512, 256, 0, stream>>>(p2, ps);
    k_ab<<<1, 256, 0, stream>>>(ps, gamma, beta, ab);

    k_route<<<2048, 256, 0, stream>>>(p2, ab, out, out + 4194304);
}